// Round 9
// baseline (15365.471 us; speedup 1.0000x reference)
//
#include <hip/hip_runtime.h>
#include <hip/hip_cooperative_groups.h>

// SimpleLSTM: V=95, H=2048, B=256, SQ=162, 15 think + 29 answer steps.
// Round 9: PERSISTENT cooperative kernel — all 206 steps in ONE launch,
// grid.sync() between steps (kills the ~45us/step launch+fill+drain fixed
// cost measured across r2-r8). Core = round-8 int8 GEMM (verified): 2-level
// i8 quant, exact i32 MFMA, 6-stage counted-vmcnt pipeline, XOR swizzle.
// c-state lives in registers (fixed block<->tile mapping across steps).

#define Hdim 2048
#define G4H  8192
#define Bsz  256
#define Vsz  95
#define SQL  162
#define TSTEPS 15
#define ASTEPS 29
#define TOT (SQL + TSTEPS + ASTEPS)

typedef signed char i8;
typedef __attribute__((ext_vector_type(4))) int i32x4;

#define S_RANGE 0.0220970869121f           // 1/sqrt(2048) = weight range
#define SWI (127.0f / S_RANGE)             // float w -> level units
#define SG  (S_RANGE / (127.0f * 127.0f))  // level-sum -> float g

namespace cg = cooperative_groups;

__device__ __forceinline__ float sigm(float x) { return 1.0f / (1.0f + expf(-x)); }

// x in level units (|x| <= 127): x ~ q1 + q2/128, q2 in [-64,64]
__device__ __forceinline__ void quant2(float xl, i8& q1, i8& q2) {
  float a = rintf(xl);
  q1 = (i8)(int)a;
  q2 = (i8)(int)rintf((xl - a) * 128.0f);
}

__device__ __forceinline__ void gll16(const i8* g, i8* l) {
  __builtin_amdgcn_global_load_lds(
      (const __attribute__((address_space(1))) void*)g,
      (__attribute__((address_space(3))) void*)l, 16, 0, 0);
}

#define VMWAIT(n) asm volatile("s_waitcnt vmcnt(" #n ")" ::: "memory")

// ---------------- init: gate-interleaved 2-level i8 split of W_hh ----------
__global__ void k_split2(const float* __restrict__ w, i8* __restrict__ w1,
                         i8* __restrict__ w2) {
  for (long i = blockIdx.x * blockDim.x + threadIdx.x; i < (long)G4H * Hdim;
       i += (long)gridDim.x * blockDim.x) {
    int n = (int)(i >> 11), k = (int)(i & 2047);
    long r = (long)((n & 3) * Hdim + (n >> 2));
    float xl = w[r * Hdim + k] * SWI;
    i8 a, b;
    quant2(xl, a, b);
    w1[i] = a;
    w2[i] = b;
  }
}

__global__ void k_prep(const float* __restrict__ W_ih, const float* __restrict__ b_ih,
                       const float* __restrict__ b_hh, float* __restrict__ wihT2,
                       float* __restrict__ bias2, float* __restrict__ hf,
                       i8* __restrict__ h1, i8* __restrict__ h2) {
  int i = blockIdx.x * 256 + threadIdx.x;
  if (i < Vsz * G4H) {
    int v = i / G4H, n = i % G4H;
    int r = (n & 3) * Hdim + (n >> 2);
    wihT2[i] = W_ih[(long)r * Vsz + v];
  }
  if (i < G4H) {
    int r = (i & 3) * Hdim + (i >> 2);
    bias2[i] = b_ih[r] + b_hh[r];
  }
  if (i < Bsz * Hdim) {
    hf[i] = 0.f;
    h1[i] = 0;
    h2[i] = 0;
  }
}

// ---------------- persistent kernel: all 206 steps ----------------
struct KP {
  const i8* w1;
  const i8* w2;
  const float* bias2;
  const float* wihT2;
  const float* Wp;
  const int* x;
  int xstride;
  float* hf;
  float* outq;
  float* lg;
  float* ic;
  float* out;
  i8* h1A;
  i8* h2A;
  i8* h1B;
  i8* h2B;
};

__global__ __launch_bounds__(512) void k_persist(KP kp) {
  cg::grid_group grid = cg::this_grid();
  __shared__ __align__(16) i8 SM[147456];  // 6 stages x 24 KB

  const int tid = threadIdx.x;
  const int wave = tid >> 6, lane = tid & 63;
  const int lin = blockIdx.x;
  // XCD-aware swizzle (T1): bijective, both M-halves co-resident per XCD.
  const int lin2 = (lin & 7) * 32 + (lin >> 3);
  const int row0 = (lin2 & 1) * 128;
  const int col0 = (lin2 >> 1) * 64;
  const int wr = wave >> 1, wc = wave & 1;  // 4 M x 2 N wave grid
  const int lr = lane & 15, lc = lane >> 4;

  // --- staging setup: 3 DMA chunks per wave per round, chunk cc = wave*3+j
  // Source k-slot pre-swizzled (conflict-free both-sides XOR, G21).
  long aoffg[3];
  int atag[3];
  const i8* bsrc[3];
  i8* ldst[3];
  {
    const int rr = lane >> 2;
    const int koff = ((lane & 3) ^ (rr & 3) ^ ((rr >> 2) & 3)) * 16;
#pragma unroll
    for (int j = 0; j < 3; ++j) {
      int cc = wave * 3 + j;
      bsrc[j] = nullptr;
      if (cc < 8)       { atag[j] = 0; aoffg[j] = (long)(row0 + cc * 16 + rr) * Hdim + koff; }
      else if (cc < 16) { atag[j] = 1; aoffg[j] = (long)(row0 + (cc - 8) * 16 + rr) * Hdim + koff; }
      else if (cc < 20) { atag[j] = 2; aoffg[j] = 0; bsrc[j] = kp.w1 + (long)(col0 + (cc - 16) * 16 + rr) * Hdim + koff; }
      else              { atag[j] = 2; aoffg[j] = 0; bsrc[j] = kp.w2 + (long)(col0 + (cc - 20) * 16 + rr) * Hdim + koff; }
      ldst[j] = SM + cc * 1024;
    }
  }

  // --- read byte-offsets within a stage (swizzled 16B k-slot per row)
  const int sl = (lc ^ (lr & 3) ^ ((lr >> 2) & 3)) * 16;
  int aoff[2], boff[2];
#pragma unroll
  for (int mf = 0; mf < 2; ++mf) aoff[mf] = (wr * 32 + mf * 16 + lr) * 64 + sl;
#pragma unroll
  for (int nf = 0; nf < 2; ++nf) boff[nf] = 16384 + (wc * 32 + nf * 16 + lr) * 64 + sl;

  // --- epilogue constants (fixed block<->tile map across all steps)
  const int h16 = tid & 15;
  const int bl32 = tid >> 4;
  const int hh_g = (col0 >> 2) + h16;
  const float bi = kp.bias2[col0 + 4 * h16 + 0];
  const float bf_ = kp.bias2[col0 + 4 * h16 + 1];
  const float bg_ = kp.bias2[col0 + 4 * h16 + 2];
  const float bo = kp.bias2[col0 + 4 * h16 + 3];

  float creg[4] = {0.f, 0.f, 0.f, 0.f};  // c-state in registers
  const char* smb = (const char*)SM;

#define STAGE(s)                                                      \
  {                                                                   \
    const int _o = ((s) % 6) * 24576;                                 \
    _Pragma("unroll") for (int j = 0; j < 3; ++j)                     \
        gll16(gsrc[j] + (s) * 64, ldst[j] + _o);                      \
  }

#define COMPUTE(kb)                                                             \
  {                                                                             \
    const char* sb = smb + ((kb) % 6) * 24576;                                  \
    i32x4 A10 = *(const i32x4*)(sb + aoff[0]);                                  \
    i32x4 A11 = *(const i32x4*)(sb + aoff[1]);                                  \
    i32x4 A20 = *(const i32x4*)(sb + 8192 + aoff[0]);                           \
    i32x4 A21 = *(const i32x4*)(sb + 8192 + aoff[1]);                           \
    i32x4 B10 = *(const i32x4*)(sb + boff[0]);                                  \
    i32x4 B11 = *(const i32x4*)(sb + boff[1]);                                  \
    i32x4 B20 = *(const i32x4*)(sb + 4096 + boff[0]);                           \
    i32x4 B21 = *(const i32x4*)(sb + 4096 + boff[1]);                           \
    __builtin_amdgcn_s_setprio(1);                                              \
    acc1[0][0] = __builtin_amdgcn_mfma_i32_16x16x64_i8(A10, B10, acc1[0][0], 0, 0, 0); \
    acc1[0][1] = __builtin_amdgcn_mfma_i32_16x16x64_i8(A10, B11, acc1[0][1], 0, 0, 0); \
    acc1[1][0] = __builtin_amdgcn_mfma_i32_16x16x64_i8(A11, B10, acc1[1][0], 0, 0, 0); \
    acc1[1][1] = __builtin_amdgcn_mfma_i32_16x16x64_i8(A11, B11, acc1[1][1], 0, 0, 0); \
    acc2[0][0] = __builtin_amdgcn_mfma_i32_16x16x64_i8(A10, B20, acc2[0][0], 0, 0, 0); \
    acc2[0][1] = __builtin_amdgcn_mfma_i32_16x16x64_i8(A10, B21, acc2[0][1], 0, 0, 0); \
    acc2[1][0] = __builtin_amdgcn_mfma_i32_16x16x64_i8(A11, B20, acc2[1][0], 0, 0, 0); \
    acc2[1][1] = __builtin_amdgcn_mfma_i32_16x16x64_i8(A11, B21, acc2[1][1], 0, 0, 0); \
    acc2[0][0] = __builtin_amdgcn_mfma_i32_16x16x64_i8(A20, B10, acc2[0][0], 0, 0, 0); \
    acc2[0][1] = __builtin_amdgcn_mfma_i32_16x16x64_i8(A20, B11, acc2[0][1], 0, 0, 0); \
    acc2[1][0] = __builtin_amdgcn_mfma_i32_16x16x64_i8(A21, B10, acc2[1][0], 0, 0, 0); \
    acc2[1][1] = __builtin_amdgcn_mfma_i32_16x16x64_i8(A21, B11, acc2[1][1], 0, 0, 0); \
    __builtin_amdgcn_s_setprio(0);                                              \
  }

  for (int t = 0; t < TOT; ++t) {
    const int pg = t & 1;
    const i8* A1 = pg ? kp.h1B : kp.h1A;
    const i8* A2 = pg ? kp.h2B : kp.h2A;
    i8* O1 = pg ? kp.h1A : kp.h1B;
    i8* O2 = pg ? kp.h2A : kp.h2B;

    if (t >= SQL + TSTEPS) {
      const int s = t - SQL - TSTEPS;
      // ---- logits: block `lin` owns batch row `lin` ----
      {
        const float* src = (s == 0 ? kp.outq : kp.hf) + (long)lin * Hdim;
        float* hl = (float*)SM;
        for (int k = tid; k < Hdim; k += 512) hl[k] = src[k];
        __syncthreads();
        for (int v = wave; v < Vsz; v += 8) {
          const float* wrow = kp.Wp + (long)v * Hdim;
          float sm = 0.f;
          for (int k = lane; k < Hdim; k += 64) sm += wrow[k] * hl[k];
#pragma unroll
          for (int off = 32; off; off >>= 1) sm += __shfl_down(sm, off);
          if (lane == 0) {
            kp.lg[lin * Vsz + v] = sm;
            kp.out[(long)s * Bsz * Vsz + lin * Vsz + v] = sm;
          }
        }
      }
      grid.sync();
      // ---- ic = logits @ W_ih.T (gate-interleaved out) ----
      {
        const int jg = lin & 31;
        const int j = jg * 256 + (tid & 255);
        float* ll = (float*)SM + (tid >> 8) * (8 * Vsz);
#pragma unroll
        for (int it = 0; it < 2; ++it) {
          const int bgp = (lin >> 5) + 8 * (2 * it + (tid >> 8));
          __syncthreads();
          for (int i = (tid & 255); i < 8 * Vsz; i += 256)
            ll[i] = kp.lg[bgp * 8 * Vsz + i];
          __syncthreads();
          float a[8] = {0, 0, 0, 0, 0, 0, 0, 0};
          for (int v = 0; v < Vsz; ++v) {
            float w = kp.wihT2[(long)v * G4H + j];
#pragma unroll
            for (int bb = 0; bb < 8; ++bb) a[bb] += ll[bb * Vsz + v] * w;
          }
#pragma unroll
          for (int bb = 0; bb < 8; ++bb)
            kp.ic[(long)(bgp * 8 + bb) * G4H + j] = a[bb];
        }
      }
      grid.sync();
    }

    // ---- GEMM: 32 K-rounds, 6-stage counted-vmcnt pipeline (r8 core) ----
    const i8* gsrc[3];
#pragma unroll
    for (int j = 0; j < 3; ++j)
      gsrc[j] = (atag[j] == 0) ? A1 + aoffg[j]
              : (atag[j] == 1) ? A2 + aoffg[j] : bsrc[j];

    i32x4 acc1[2][2] = {};
    i32x4 acc2[2][2] = {};

    STAGE(0); STAGE(1); STAGE(2); STAGE(3); STAGE(4);
    for (int kb = 0; kb < 27; ++kb) {
      VMWAIT(12);
      __builtin_amdgcn_s_barrier();
      STAGE(kb + 5);
      COMPUTE(kb);
    }
    VMWAIT(12); __builtin_amdgcn_s_barrier(); COMPUTE(27);
    VMWAIT(9);  __builtin_amdgcn_s_barrier(); COMPUTE(28);
    VMWAIT(6);  __builtin_amdgcn_s_barrier(); COMPUTE(29);
    VMWAIT(3);  __builtin_amdgcn_s_barrier(); COMPUTE(30);
    VMWAIT(0);  __builtin_amdgcn_s_barrier(); COMPUTE(31);

    // ---- epilogue: scaled g-tile via LDS, fused gates, c in registers ----
    __syncthreads();
    float* gt = (float*)SM;
#pragma unroll
    for (int mf = 0; mf < 2; ++mf)
#pragma unroll
      for (int nf = 0; nf < 2; ++nf) {
        int col = wc * 32 + nf * 16 + lr;
#pragma unroll
        for (int i = 0; i < 4; ++i) {
          int row = wr * 32 + mf * 16 + lc * 4 + i;
          gt[row * 68 + col] =
              ((float)acc1[mf][nf][i] + (float)acc2[mf][nf][i] * 0.0078125f) * SG;
        }
      }
    __syncthreads();

#pragma unroll
    for (int pr = 0; pr < 4; ++pr) {
      int brow = pr * 32 + bl32;
      int bg = row0 + brow;
      const float* gr = &gt[brow * 68 + 4 * h16];
      float xi = gr[0] + bi, xf = gr[1] + bf_, xg = gr[2] + bg_, xo = gr[3] + bo;
      if (t < SQL) {
        int tok = kp.x[(bg * SQL + t) * kp.xstride];
        const float* wv = kp.wihT2 + (long)tok * G4H + col0 + 4 * h16;
        xi += wv[0]; xf += wv[1]; xg += wv[2]; xo += wv[3];
      } else if (t >= SQL + TSTEPS) {
        const float* iv = kp.ic + (long)bg * G4H + col0 + 4 * h16;
        xi += iv[0]; xf += iv[1]; xg += iv[2]; xo += iv[3];
      }
      float cn = sigm(xf) * creg[pr] + sigm(xi) * tanhf(xg);
      float hn = sigm(xo) * tanhf(cn);
      creg[pr] = cn;
      long ci = (long)bg * Hdim + hh_g;
      kp.hf[ci] = hn;
      if (t == SQL - 1) kp.outq[ci] = hn;
      i8 q1, q2;
      quant2(hn * 127.0f, q1, q2);
      O1[ci] = q1;
      O2[ci] = q2;
    }
    grid.sync();
  }
#undef STAGE
#undef COMPUTE
}

// ---------------- host ----------------
extern "C" void kernel_launch(void* const* d_in, const int* in_sizes, int n_in,
                              void* d_out, int out_size, void* d_ws, size_t ws_size,
                              hipStream_t stream) {
  const int* x = (const int*)d_in[0];
  const float* W_ih = (const float*)d_in[1];
  const float* W_hh = (const float*)d_in[2];
  const float* b_ih = (const float*)d_in[3];
  const float* b_hh = (const float*)d_in[4];
  const float* W_proj = (const float*)d_in[5];
  float* out = (float*)d_out;

  int xstride = (in_sizes[0] > Bsz * SQL) ? 2 : 1;

  // workspace layout (~50 MB)
  i8* w1 = (i8*)d_ws;
  i8* w2 = w1 + (long)G4H * Hdim;
  float* wihT2 = (float*)(w2 + (long)G4H * Hdim);
  float* bias2 = wihT2 + (long)Vsz * G4H;
  float* ic = bias2 + G4H;
  float* hf = ic + (long)Bsz * G4H;
  float* outq = hf + (long)Bsz * Hdim;
  float* lg = outq + (long)Bsz * Hdim;
  i8* h1A = (i8*)(lg + Bsz * Vsz);
  i8* h2A = h1A + (long)Bsz * Hdim;
  i8* h1B = h2A + (long)Bsz * Hdim;
  i8* h2B = h1B + (long)Bsz * Hdim;

  k_split2<<<4096, 256, 0, stream>>>(W_hh, w1, w2);
  k_prep<<<3040, 256, 0, stream>>>(W_ih, b_ih, b_hh, wihT2, bias2, hf, h1A, h2A);

  KP kp;
  kp.w1 = w1;
  kp.w2 = w2;
  kp.bias2 = bias2;
  kp.wihT2 = wihT2;
  kp.Wp = W_proj;
  kp.x = x;
  kp.xstride = xstride;
  kp.hf = hf;
  kp.outq = outq;
  kp.lg = lg;
  kp.ic = ic;
  kp.out = out;
  kp.h1A = h1A;
  kp.h2A = h2A;
  kp.h1B = h1B;
  kp.h2B = h2B;

  void* kargs[] = {(void*)&kp};
  hipLaunchCooperativeKernel((void*)k_persist, dim3(256), dim3(512), kargs, 0,
                             stream);
}

// Round 10
// 11343.452 us; speedup vs baseline: 1.3546x; 1.3546x over previous
//
#include <hip/hip_runtime.h>

// SimpleLSTM: V=95, H=2048, B=256, SQ=162, 15 think + 29 answer steps.
// Round 10: multi-launch (launches measured cheaper than grid.sync) +
// REG-STAGED depth-3 queue (global->VGPR->ds_write, counted vmcnt via
// compiler deps, lgkmcnt-only waits at barriers, 48 KB LDS) + k_ic fused
// into k_step epilogue. Numerics: 2-level int8, exact i32 MFMA (r8-proven).

#define Hdim 2048
#define G4H  8192
#define Bsz  256
#define Vsz  95
#define SQL  162
#define TSTEPS 15
#define ASTEPS 29

typedef signed char i8;
typedef __attribute__((ext_vector_type(4))) int i32x4;

#define S_RANGE 0.0220970869121f           // 1/sqrt(2048) = weight range
#define SWI (127.0f / S_RANGE)             // float w -> level units
#define SG  (S_RANGE / (127.0f * 127.0f))  // level-sum -> float g

__device__ __forceinline__ float sigm(float x) { return 1.0f / (1.0f + expf(-x)); }

// x in level units (|x| <= 127): x ~ q1 + q2/128, q2 in [-64,64]
__device__ __forceinline__ void quant2(float xl, i8& q1, i8& q2) {
  float a = rintf(xl);
  q1 = (i8)(int)a;
  q2 = (i8)(int)rintf((xl - a) * 128.0f);
}

#define LGKM_BAR                                            \
  asm volatile("s_waitcnt lgkmcnt(0)" ::: "memory");        \
  __builtin_amdgcn_s_barrier();

// ---------------- init: gate-interleaved 2-level i8 split of W_hh ----------
__global__ void k_split2(const float* __restrict__ w, i8* __restrict__ w1,
                         i8* __restrict__ w2) {
  for (long i = blockIdx.x * blockDim.x + threadIdx.x; i < (long)G4H * Hdim;
       i += (long)gridDim.x * blockDim.x) {
    int n = (int)(i >> 11), k = (int)(i & 2047);
    long r = (long)((n & 3) * Hdim + (n >> 2));
    float xl = w[r * Hdim + k] * SWI;
    i8 a, b;
    quant2(xl, a, b);
    w1[i] = a;
    w2[i] = b;
  }
}

__global__ void k_prep(const float* __restrict__ W_ih, const float* __restrict__ b_ih,
                       const float* __restrict__ b_hh, float* __restrict__ wihT2,
                       float* __restrict__ bias2, float* __restrict__ hf,
                       i8* __restrict__ h1, i8* __restrict__ h2) {
  int i = blockIdx.x * 256 + threadIdx.x;
  if (i < Vsz * G4H) {
    int v = i / G4H, n = i % G4H;
    int r = (n & 3) * Hdim + (n >> 2);
    wihT2[i] = W_ih[(long)r * Vsz + v];
  }
  if (i < G4H) {
    int r = (i & 3) * Hdim + (i >> 2);
    bias2[i] = b_ih[r] + b_hh[r];
  }
  if (i < Bsz * Hdim) {
    hf[i] = 0.f;
    h1[i] = 0;
    h2[i] = 0;
  }
}

// ---------------- fused step: g = h@W_hh.T (+input) -> gates -> h,c ----------
// Tile BM=128 BN=64 BK=64, grid 256 blocks, 8 waves (4Mx2N, wave 32x32).
// Reg-staged: 3 chunks (16B/lane) per wave per round, depth-3 reg queue
// (qA/qB/qC), 2-stage LDS [A1 8K|A2 8K|B1 4K|B2 4K] x2 = 48KB.
// mode 1: += one-hot gather; mode 2: += logits @ W_ih.T computed in epilogue.
__global__ __launch_bounds__(512) void k_step(
    const i8* __restrict__ a1p, const i8* __restrict__ a2p,
    const i8* __restrict__ b1p, const i8* __restrict__ b2p,
    const float* __restrict__ bias2, const float* __restrict__ wihT2,
    const float* __restrict__ lgp, const int* __restrict__ x, int tstep,
    int xstride, int mode, float* __restrict__ c, float* __restrict__ hf,
    i8* __restrict__ o1, i8* __restrict__ o2) {
  __shared__ __align__(16) i8 SM[49152];  // 2 stages x 24 KB

  const int tid = threadIdx.x;
  const int wave = tid >> 6, lane = tid & 63;

  // XCD-aware swizzle (T1): 256 blocks, bijective; both M-halves co-resident.
  const int lin = blockIdx.x;
  const int lin2 = (lin & 7) * 32 + (lin >> 3);
  const int row0 = (lin2 & 1) * 128;
  const int col0 = (lin2 >> 1) * 64;

  const int wr = wave >> 1, wc = wave & 1;  // 4 M x 2 N wave grid
  const int lr = lane & 15, lc = lane >> 4;

  // --- staging: 3 chunks per wave per round, chunk cc = wave*3+j
  // chunk = 16 rows x 64 k-bytes (1KB); lane -> row lane>>2, 16B slot lane&3.
  // Source k-slot pre-swizzled (conflict-free both-sides XOR, G21).
  const i8* gsrc[3];
  i8* wdst[3];
  {
    const int rr = lane >> 2;
    const int koff = ((lane & 3) ^ (rr & 3) ^ ((rr >> 2) & 3)) * 16;
#pragma unroll
    for (int j = 0; j < 3; ++j) {
      int cc = wave * 3 + j;
      const i8* base;
      long rg;
      if (cc < 8)       { base = a1p; rg = row0 + cc * 16; }
      else if (cc < 16) { base = a2p; rg = row0 + (cc - 8) * 16; }
      else if (cc < 20) { base = b1p; rg = col0 + (cc - 16) * 16; }
      else              { base = b2p; rg = col0 + (cc - 20) * 16; }
      gsrc[j] = base + (rg + rr) * (long)Hdim + koff;
      wdst[j] = SM + cc * 1024 + lane * 16;  // linear LDS, 16B per lane
    }
  }

  // --- read byte-offsets within a stage (swizzled 16B k-slot per row)
  const int sl = (lc ^ (lr & 3) ^ ((lr >> 2) & 3)) * 16;
  int aoff[2], boff[2];
#pragma unroll
  for (int mf = 0; mf < 2; ++mf) aoff[mf] = (wr * 32 + mf * 16 + lr) * 64 + sl;
#pragma unroll
  for (int nf = 0; nf < 2; ++nf) boff[nf] = 16384 + (wc * 32 + nf * 16 + lr) * 64 + sl;

  i32x4 acc1[2][2] = {};
  i32x4 acc2[2][2] = {};
  const char* smb = (const char*)SM;
  i32x4 qA[3], qB[3], qC[3];

#define LOADQ(q, s)                                                   \
  { _Pragma("unroll") for (int j = 0; j < 3; ++j)                     \
        q[j] = *(const i32x4*)(gsrc[j] + (long)(s) * 64); }
#define WRITEQ(q, s)                                                  \
  { _Pragma("unroll") for (int j = 0; j < 3; ++j)                     \
        *(i32x4*)(wdst[j] + (((s) & 1) * 24576)) = q[j]; }

#define COMPUTE(kb)                                                             \
  {                                                                             \
    const char* sb = smb + ((kb) & 1) * 24576;                                  \
    i32x4 A10 = *(const i32x4*)(sb + aoff[0]);                                  \
    i32x4 A11 = *(const i32x4*)(sb + aoff[1]);                                  \
    i32x4 A20 = *(const i32x4*)(sb + 8192 + aoff[0]);                           \
    i32x4 A21 = *(const i32x4*)(sb + 8192 + aoff[1]);                           \
    i32x4 B10 = *(const i32x4*)(sb + boff[0]);                                  \
    i32x4 B11 = *(const i32x4*)(sb + boff[1]);                                  \
    i32x4 B20 = *(const i32x4*)(sb + 4096 + boff[0]);                           \
    i32x4 B21 = *(const i32x4*)(sb + 4096 + boff[1]);                           \
    __builtin_amdgcn_s_setprio(1);                                              \
    acc1[0][0] = __builtin_amdgcn_mfma_i32_16x16x64_i8(A10, B10, acc1[0][0], 0, 0, 0); \
    acc1[0][1] = __builtin_amdgcn_mfma_i32_16x16x64_i8(A10, B11, acc1[0][1], 0, 0, 0); \
    acc1[1][0] = __builtin_amdgcn_mfma_i32_16x16x64_i8(A11, B10, acc1[1][0], 0, 0, 0); \
    acc1[1][1] = __builtin_amdgcn_mfma_i32_16x16x64_i8(A11, B11, acc1[1][1], 0, 0, 0); \
    acc2[0][0] = __builtin_amdgcn_mfma_i32_16x16x64_i8(A10, B20, acc2[0][0], 0, 0, 0); \
    acc2[0][1] = __builtin_amdgcn_mfma_i32_16x16x64_i8(A10, B21, acc2[0][1], 0, 0, 0); \
    acc2[1][0] = __builtin_amdgcn_mfma_i32_16x16x64_i8(A11, B20, acc2[1][0], 0, 0, 0); \
    acc2[1][1] = __builtin_amdgcn_mfma_i32_16x16x64_i8(A11, B21, acc2[1][1], 0, 0, 0); \
    acc2[0][0] = __builtin_amdgcn_mfma_i32_16x16x64_i8(A20, B10, acc2[0][0], 0, 0, 0); \
    acc2[0][1] = __builtin_amdgcn_mfma_i32_16x16x64_i8(A20, B11, acc2[0][1], 0, 0, 0); \
    acc2[1][0] = __builtin_amdgcn_mfma_i32_16x16x64_i8(A21, B10, acc2[1][0], 0, 0, 0); \
    acc2[1][1] = __builtin_amdgcn_mfma_i32_16x16x64_i8(A21, B11, acc2[1][1], 0, 0, 0); \
    __builtin_amdgcn_s_setprio(0);                                              \
  }

  // prologue: fill depth-3 reg queue, commit stage 0 to buf0
  LOADQ(qA, 0); LOADQ(qB, 1); LOADQ(qC, 2);
  WRITEQ(qA, 0);
  LGKM_BAR;

  // main loop: round kb loads stage kb+3 into q[kb%3], writes stage kb+1
  // from q[(kb+1)%3] into buf (kb+1)&1, computes stage kb from buf kb&1.
  // vmcnt waits are compiler-derived (counted, never 0); lgkm-only barrier.
  for (int t5 = 0; t5 < 5; ++t5) {
    const int kb0 = t5 * 6;
    if (kb0 + 3 <= 31) LOADQ(qA, kb0 + 3);
    WRITEQ(qB, kb0 + 1); COMPUTE(kb0); LGKM_BAR;
    if (kb0 + 4 <= 31) LOADQ(qB, kb0 + 4);
    WRITEQ(qC, kb0 + 2); COMPUTE(kb0 + 1); LGKM_BAR;
    if (kb0 + 5 <= 31) LOADQ(qC, kb0 + 5);
    WRITEQ(qA, kb0 + 3); COMPUTE(kb0 + 2); LGKM_BAR;
    if (kb0 + 6 <= 31) LOADQ(qA, kb0 + 6);
    WRITEQ(qB, kb0 + 4); COMPUTE(kb0 + 3); LGKM_BAR;
    if (kb0 + 7 <= 31) LOADQ(qB, kb0 + 7);
    WRITEQ(qC, kb0 + 5); COMPUTE(kb0 + 4); LGKM_BAR;
    if (kb0 + 8 <= 31) LOADQ(qC, kb0 + 8);
    WRITEQ(qA, kb0 + 6); COMPUTE(kb0 + 5); LGKM_BAR;
  }
  // tail: rounds 30, 31 (stage 31 sits in qB, loaded at round 28)
  WRITEQ(qB, 31); COMPUTE(30); LGKM_BAR;
  COMPUTE(31);

  // --- epilogue: scaled g-tile via LDS (padded stride 68), fused gates
  __syncthreads();
  float* gt = (float*)SM;
#pragma unroll
  for (int mf = 0; mf < 2; ++mf)
#pragma unroll
    for (int nf = 0; nf < 2; ++nf) {
      int col = wc * 32 + nf * 16 + lr;
#pragma unroll
      for (int i = 0; i < 4; ++i) {
        int row = wr * 32 + mf * 16 + lc * 4 + i;
        gt[row * 68 + col] =
            ((float)acc1[mf][nf][i] + (float)acc2[mf][nf][i] * 0.0078125f) * SG;
      }
    }
  __syncthreads();

  const int h16 = tid & 15;    // local hh (16 per block)
  const int bl32 = tid >> 4;   // 0..31 row group
  const int hh_g = (col0 >> 2) + h16;
  const float bi = bias2[col0 + 4 * h16 + 0];
  const float bf_ = bias2[col0 + 4 * h16 + 1];
  const float bg_ = bias2[col0 + 4 * h16 + 2];
  const float bo = bias2[col0 + 4 * h16 + 3];

  // fused ic (mode 2): ai..ao[pr] = sum_v lg[bg][v] * wihT2[v][col..col+3]
  float ai[4] = {0, 0, 0, 0}, af[4] = {0, 0, 0, 0};
  float ag[4] = {0, 0, 0, 0}, ao[4] = {0, 0, 0, 0};
  if (mode == 2) {
    const float* wv0 = wihT2 + col0 + 4 * h16;
    for (int v = 0; v < Vsz; ++v) {
      const float* w4 = wv0 + (long)v * G4H;
      float w0 = w4[0], w1 = w4[1], w2 = w4[2], w3 = w4[3];
#pragma unroll
      for (int pr = 0; pr < 4; ++pr) {
        float l = lgp[(row0 + pr * 32 + bl32) * Vsz + v];
        ai[pr] += l * w0; af[pr] += l * w1; ag[pr] += l * w2; ao[pr] += l * w3;
      }
    }
  }

#pragma unroll
  for (int pr = 0; pr < 4; ++pr) {
    int brow = pr * 32 + bl32;
    int bg = row0 + brow;
    const float* gr = &gt[brow * 68 + 4 * h16];
    float xi = gr[0] + bi + ai[pr], xf = gr[1] + bf_ + af[pr];
    float xg = gr[2] + bg_ + ag[pr], xo = gr[3] + bo + ao[pr];
    if (mode == 1) {
      int tok = x[(bg * SQL + tstep) * xstride];
      const float* wv = wihT2 + (long)tok * G4H + col0 + 4 * h16;
      xi += wv[0]; xf += wv[1]; xg += wv[2]; xo += wv[3];
    }
    long ci = (long)bg * Hdim + hh_g;
    float cn = sigm(xf) * c[ci] + sigm(xi) * tanhf(xg);
    float hn = sigm(xo) * tanhf(cn);
    c[ci] = cn;
    hf[ci] = hn;
    i8 q1, q2;
    quant2(hn * 127.0f, q1, q2);
    o1[ci] = q1;
    o2[ci] = q2;
  }
#undef LOADQ
#undef WRITEQ
#undef COMPUTE
}

// ---------------- logits = src @ W_proj.T (fp32) ----------------
__global__ __launch_bounds__(256) void k_logits(const float* __restrict__ src,
                                                const float* __restrict__ Wp,
                                                float* __restrict__ lg,
                                                float* __restrict__ outp) {
  __shared__ float hl[Hdim];
  int b = blockIdx.x, tid = threadIdx.x;
  for (int k = tid; k < Hdim; k += 256) hl[k] = src[(long)b * Hdim + k];
  __syncthreads();
  int wv = tid >> 6, ln = tid & 63;
  for (int v = wv; v < Vsz; v += 4) {
    const float* wrow = Wp + (long)v * Hdim;
    float s = 0.f;
    for (int k = ln; k < Hdim; k += 64) s += wrow[k] * hl[k];
#pragma unroll
    for (int off = 32; off; off >>= 1) s += __shfl_down(s, off);
    if (ln == 0) {
      lg[b * Vsz + v] = s;
      outp[b * Vsz + v] = s;
    }
  }
}

// ---------------- host ----------------
extern "C" void kernel_launch(void* const* d_in, const int* in_sizes, int n_in,
                              void* d_out, int out_size, void* d_ws, size_t ws_size,
                              hipStream_t stream) {
  const int* x = (const int*)d_in[0];
  const float* W_ih = (const float*)d_in[1];
  const float* W_hh = (const float*)d_in[2];
  const float* b_ih = (const float*)d_in[3];
  const float* b_hh = (const float*)d_in[4];
  const float* W_proj = (const float*)d_in[5];
  float* out = (float*)d_out;

  int xstride = (in_sizes[0] > Bsz * SQL) ? 2 : 1;

  // workspace layout (~45 MB)
  i8* w1 = (i8*)d_ws;
  i8* w2 = w1 + (long)G4H * Hdim;
  float* wihT2 = (float*)(w2 + (long)G4H * Hdim);
  float* bias2 = wihT2 + (long)Vsz * G4H;
  float* hf = bias2 + G4H;
  float* c = hf + (long)Bsz * Hdim;
  float* outq = c + (long)Bsz * Hdim;
  float* lg = outq + (long)Bsz * Hdim;
  i8* h1A = (i8*)(lg + Bsz * Vsz);
  i8* h2A = h1A + (long)Bsz * Hdim;
  i8* h1B = h2A + (long)Bsz * Hdim;
  i8* h2B = h1B + (long)Bsz * Hdim;

  k_split2<<<4096, 256, 0, stream>>>(W_hh, w1, w2);
  k_prep<<<3040, 256, 0, stream>>>(W_ih, b_ih, b_hh, wihT2, bias2, hf, h1A, h2A);

  // zero c (poisoned workspace)
  hipMemsetAsync(c, 0, (long)Bsz * Hdim * sizeof(float), stream);

  i8* i1[2] = {h1A, h1B};
  i8* i2[2] = {h2A, h2B};
  int pp = 0;

  // Phase 1: question (one-hot gather fused into epilogue)
  for (int t = 0; t < SQL; ++t) {
    k_step<<<256, 512, 0, stream>>>(i1[pp], i2[pp], w1, w2, bias2, wihT2,
                                    nullptr, x, t, xstride, 1, c, hf,
                                    i1[pp ^ 1], i2[pp ^ 1]);
    pp ^= 1;
  }
  hipMemcpyAsync(outq, hf, (long)Bsz * Hdim * sizeof(float),
                 hipMemcpyDeviceToDevice, stream);

  // Phase 2: thinking (zero input)
  for (int t = 0; t < TSTEPS; ++t) {
    k_step<<<256, 512, 0, stream>>>(i1[pp], i2[pp], w1, w2, bias2, wihT2,
                                    nullptr, nullptr, 0, 1, 0, c, hf,
                                    i1[pp ^ 1], i2[pp ^ 1]);
    pp ^= 1;
  }

  // Phase 3: autoregressive answer (logits fed back; ic fused in epilogue)
  for (int s = 0; s < ASTEPS; ++s) {
    const float* src = (s == 0) ? outq : hf;
    k_logits<<<Bsz, 256, 0, stream>>>(src, W_proj, lg, out + (long)s * Bsz * Vsz);
    k_step<<<256, 512, 0, stream>>>(i1[pp], i2[pp], w1, w2, bias2, wihT2,
                                    lg, nullptr, 0, 1, 2, c, hf,
                                    i1[pp ^ 1], i2[pp ^ 1]);
    pp ^= 1;
  }
}

// Round 11
// 5842.880 us; speedup vs baseline: 2.6298x; 1.9414x over previous
//
#include <hip/hip_runtime.h>

// SimpleLSTM: V=95, H=2048, B=256, SQ=162, 15 think + 29 answer steps.
// Round 11: k_logits REWRITE — r10 counters showed k_logits = 273us x 29
// = 7.9ms of the 11.3ms total (serial dependent-load chain, 1 wave/SIMD,
// MfmaUtil 0 / VALU 2.5% / HBM 0.2%). New version: h row cached in 8
// float4 regs, 8-deep unrolled coalesced W_proj loads, wave shuffle reduce.
// k_step (16us/step, passing) carried over from round 10 UNCHANGED.

#define Hdim 2048
#define G4H  8192
#define Bsz  256
#define Vsz  95
#define SQL  162
#define TSTEPS 15
#define ASTEPS 29

typedef signed char i8;
typedef __attribute__((ext_vector_type(4))) int i32x4;

#define S_RANGE 0.0220970869121f           // 1/sqrt(2048) = weight range
#define SWI (127.0f / S_RANGE)             // float w -> level units
#define SG  (S_RANGE / (127.0f * 127.0f))  // level-sum -> float g

__device__ __forceinline__ float sigm(float x) { return 1.0f / (1.0f + expf(-x)); }

// x in level units (|x| <= 127): x ~ q1 + q2/128, q2 in [-64,64]
__device__ __forceinline__ void quant2(float xl, i8& q1, i8& q2) {
  float a = rintf(xl);
  q1 = (i8)(int)a;
  q2 = (i8)(int)rintf((xl - a) * 128.0f);
}

#define LGKM_BAR                                            \
  asm volatile("s_waitcnt lgkmcnt(0)" ::: "memory");        \
  __builtin_amdgcn_s_barrier();

// ---------------- init: gate-interleaved 2-level i8 split of W_hh ----------
__global__ void k_split2(const float* __restrict__ w, i8* __restrict__ w1,
                         i8* __restrict__ w2) {
  for (long i = blockIdx.x * blockDim.x + threadIdx.x; i < (long)G4H * Hdim;
       i += (long)gridDim.x * blockDim.x) {
    int n = (int)(i >> 11), k = (int)(i & 2047);
    long r = (long)((n & 3) * Hdim + (n >> 2));
    float xl = w[r * Hdim + k] * SWI;
    i8 a, b;
    quant2(xl, a, b);
    w1[i] = a;
    w2[i] = b;
  }
}

__global__ void k_prep(const float* __restrict__ W_ih, const float* __restrict__ b_ih,
                       const float* __restrict__ b_hh, float* __restrict__ wihT2,
                       float* __restrict__ bias2, float* __restrict__ hf,
                       i8* __restrict__ h1, i8* __restrict__ h2) {
  int i = blockIdx.x * 256 + threadIdx.x;
  if (i < Vsz * G4H) {
    int v = i / G4H, n = i % G4H;
    int r = (n & 3) * Hdim + (n >> 2);
    wihT2[i] = W_ih[(long)r * Vsz + v];
  }
  if (i < G4H) {
    int r = (i & 3) * Hdim + (i >> 2);
    bias2[i] = b_ih[r] + b_hh[r];
  }
  if (i < Bsz * Hdim) {
    hf[i] = 0.f;
    h1[i] = 0;
    h2[i] = 0;
  }
}

// ---------------- fused step: g = h@W_hh.T (+input) -> gates -> h,c ----------
// Tile BM=128 BN=64 BK=64, grid 256 blocks, 8 waves (4Mx2N, wave 32x32).
// Reg-staged: 3 chunks (16B/lane) per wave per round, depth-3 reg queue
// (qA/qB/qC), 2-stage LDS [A1 8K|A2 8K|B1 4K|B2 4K] x2 = 48KB.
// mode 1: += one-hot gather; mode 2: += logits @ W_ih.T computed in epilogue.
__global__ __launch_bounds__(512) void k_step(
    const i8* __restrict__ a1p, const i8* __restrict__ a2p,
    const i8* __restrict__ b1p, const i8* __restrict__ b2p,
    const float* __restrict__ bias2, const float* __restrict__ wihT2,
    const float* __restrict__ lgp, const int* __restrict__ x, int tstep,
    int xstride, int mode, float* __restrict__ c, float* __restrict__ hf,
    i8* __restrict__ o1, i8* __restrict__ o2) {
  __shared__ __align__(16) i8 SM[49152];  // 2 stages x 24 KB

  const int tid = threadIdx.x;
  const int wave = tid >> 6, lane = tid & 63;

  // XCD-aware swizzle (T1): 256 blocks, bijective; both M-halves co-resident.
  const int lin = blockIdx.x;
  const int lin2 = (lin & 7) * 32 + (lin >> 3);
  const int row0 = (lin2 & 1) * 128;
  const int col0 = (lin2 >> 1) * 64;

  const int wr = wave >> 1, wc = wave & 1;  // 4 M x 2 N wave grid
  const int lr = lane & 15, lc = lane >> 4;

  // --- staging: 3 chunks per wave per round, chunk cc = wave*3+j
  // chunk = 16 rows x 64 k-bytes (1KB); lane -> row lane>>2, 16B slot lane&3.
  // Source k-slot pre-swizzled (conflict-free both-sides XOR, G21).
  const i8* gsrc[3];
  i8* wdst[3];
  {
    const int rr = lane >> 2;
    const int koff = ((lane & 3) ^ (rr & 3) ^ ((rr >> 2) & 3)) * 16;
#pragma unroll
    for (int j = 0; j < 3; ++j) {
      int cc = wave * 3 + j;
      const i8* base;
      long rg;
      if (cc < 8)       { base = a1p; rg = row0 + cc * 16; }
      else if (cc < 16) { base = a2p; rg = row0 + (cc - 8) * 16; }
      else if (cc < 20) { base = b1p; rg = col0 + (cc - 16) * 16; }
      else              { base = b2p; rg = col0 + (cc - 20) * 16; }
      gsrc[j] = base + (rg + rr) * (long)Hdim + koff;
      wdst[j] = SM + cc * 1024 + lane * 16;  // linear LDS, 16B per lane
    }
  }

  // --- read byte-offsets within a stage (swizzled 16B k-slot per row)
  const int sl = (lc ^ (lr & 3) ^ ((lr >> 2) & 3)) * 16;
  int aoff[2], boff[2];
#pragma unroll
  for (int mf = 0; mf < 2; ++mf) aoff[mf] = (wr * 32 + mf * 16 + lr) * 64 + sl;
#pragma unroll
  for (int nf = 0; nf < 2; ++nf) boff[nf] = 16384 + (wc * 32 + nf * 16 + lr) * 64 + sl;

  i32x4 acc1[2][2] = {};
  i32x4 acc2[2][2] = {};
  const char* smb = (const char*)SM;
  i32x4 qA[3], qB[3], qC[3];

#define LOADQ(q, s)                                                   \
  { _Pragma("unroll") for (int j = 0; j < 3; ++j)                     \
        q[j] = *(const i32x4*)(gsrc[j] + (long)(s) * 64); }
#define WRITEQ(q, s)                                                  \
  { _Pragma("unroll") for (int j = 0; j < 3; ++j)                     \
        *(i32x4*)(wdst[j] + (((s) & 1) * 24576)) = q[j]; }

#define COMPUTE(kb)                                                             \
  {                                                                             \
    const char* sb = smb + ((kb) & 1) * 24576;                                  \
    i32x4 A10 = *(const i32x4*)(sb + aoff[0]);                                  \
    i32x4 A11 = *(const i32x4*)(sb + aoff[1]);                                  \
    i32x4 A20 = *(const i32x4*)(sb + 8192 + aoff[0]);                           \
    i32x4 A21 = *(const i32x4*)(sb + 8192 + aoff[1]);                           \
    i32x4 B10 = *(const i32x4*)(sb + boff[0]);                                  \
    i32x4 B11 = *(const i32x4*)(sb + boff[1]);                                  \
    i32x4 B20 = *(const i32x4*)(sb + 4096 + boff[0]);                           \
    i32x4 B21 = *(const i32x4*)(sb + 4096 + boff[1]);                           \
    __builtin_amdgcn_s_setprio(1);                                              \
    acc1[0][0] = __builtin_amdgcn_mfma_i32_16x16x64_i8(A10, B10, acc1[0][0], 0, 0, 0); \
    acc1[0][1] = __builtin_amdgcn_mfma_i32_16x16x64_i8(A10, B11, acc1[0][1], 0, 0, 0); \
    acc1[1][0] = __builtin_amdgcn_mfma_i32_16x16x64_i8(A11, B10, acc1[1][0], 0, 0, 0); \
    acc1[1][1] = __builtin_amdgcn_mfma_i32_16x16x64_i8(A11, B11, acc1[1][1], 0, 0, 0); \
    acc2[0][0] = __builtin_amdgcn_mfma_i32_16x16x64_i8(A10, B20, acc2[0][0], 0, 0, 0); \
    acc2[0][1] = __builtin_amdgcn_mfma_i32_16x16x64_i8(A10, B21, acc2[0][1], 0, 0, 0); \
    acc2[1][0] = __builtin_amdgcn_mfma_i32_16x16x64_i8(A11, B20, acc2[1][0], 0, 0, 0); \
    acc2[1][1] = __builtin_amdgcn_mfma_i32_16x16x64_i8(A11, B21, acc2[1][1], 0, 0, 0); \
    acc2[0][0] = __builtin_amdgcn_mfma_i32_16x16x64_i8(A20, B10, acc2[0][0], 0, 0, 0); \
    acc2[0][1] = __builtin_amdgcn_mfma_i32_16x16x64_i8(A20, B11, acc2[0][1], 0, 0, 0); \
    acc2[1][0] = __builtin_amdgcn_mfma_i32_16x16x64_i8(A21, B10, acc2[1][0], 0, 0, 0); \
    acc2[1][1] = __builtin_amdgcn_mfma_i32_16x16x64_i8(A21, B11, acc2[1][1], 0, 0, 0); \
    __builtin_amdgcn_s_setprio(0);                                              \
  }

  // prologue: fill depth-3 reg queue, commit stage 0 to buf0
  LOADQ(qA, 0); LOADQ(qB, 1); LOADQ(qC, 2);
  WRITEQ(qA, 0);
  LGKM_BAR;

  // main loop: round kb loads stage kb+3 into q[kb%3], writes stage kb+1
  // from q[(kb+1)%3] into buf (kb+1)&1, computes stage kb from buf kb&1.
  // vmcnt waits are compiler-derived (counted, never 0); lgkm-only barrier.
  for (int t5 = 0; t5 < 5; ++t5) {
    const int kb0 = t5 * 6;
    if (kb0 + 3 <= 31) LOADQ(qA, kb0 + 3);
    WRITEQ(qB, kb0 + 1); COMPUTE(kb0); LGKM_BAR;
    if (kb0 + 4 <= 31) LOADQ(qB, kb0 + 4);
    WRITEQ(qC, kb0 + 2); COMPUTE(kb0 + 1); LGKM_BAR;
    if (kb0 + 5 <= 31) LOADQ(qC, kb0 + 5);
    WRITEQ(qA, kb0 + 3); COMPUTE(kb0 + 2); LGKM_BAR;
    if (kb0 + 6 <= 31) LOADQ(qA, kb0 + 6);
    WRITEQ(qB, kb0 + 4); COMPUTE(kb0 + 3); LGKM_BAR;
    if (kb0 + 7 <= 31) LOADQ(qB, kb0 + 7);
    WRITEQ(qC, kb0 + 5); COMPUTE(kb0 + 4); LGKM_BAR;
    if (kb0 + 8 <= 31) LOADQ(qC, kb0 + 8);
    WRITEQ(qA, kb0 + 6); COMPUTE(kb0 + 5); LGKM_BAR;
  }
  // tail: rounds 30, 31 (stage 31 sits in qB, loaded at round 28)
  WRITEQ(qB, 31); COMPUTE(30); LGKM_BAR;
  COMPUTE(31);

  // --- epilogue: scaled g-tile via LDS (padded stride 68), fused gates
  __syncthreads();
  float* gt = (float*)SM;
#pragma unroll
  for (int mf = 0; mf < 2; ++mf)
#pragma unroll
    for (int nf = 0; nf < 2; ++nf) {
      int col = wc * 32 + nf * 16 + lr;
#pragma unroll
      for (int i = 0; i < 4; ++i) {
        int row = wr * 32 + mf * 16 + lc * 4 + i;
        gt[row * 68 + col] =
            ((float)acc1[mf][nf][i] + (float)acc2[mf][nf][i] * 0.0078125f) * SG;
      }
    }
  __syncthreads();

  const int h16 = tid & 15;    // local hh (16 per block)
  const int bl32 = tid >> 4;   // 0..31 row group
  const int hh_g = (col0 >> 2) + h16;
  const float bi = bias2[col0 + 4 * h16 + 0];
  const float bf_ = bias2[col0 + 4 * h16 + 1];
  const float bg_ = bias2[col0 + 4 * h16 + 2];
  const float bo = bias2[col0 + 4 * h16 + 3];

  // fused ic (mode 2): ai..ao[pr] = sum_v lg[bg][v] * wihT2[v][col..col+3]
  float ai[4] = {0, 0, 0, 0}, af[4] = {0, 0, 0, 0};
  float ag[4] = {0, 0, 0, 0}, ao[4] = {0, 0, 0, 0};
  if (mode == 2) {
    const float* wv0 = wihT2 + col0 + 4 * h16;
    for (int v = 0; v < Vsz; ++v) {
      const float* w4 = wv0 + (long)v * G4H;
      float w0 = w4[0], w1 = w4[1], w2 = w4[2], w3 = w4[3];
#pragma unroll
      for (int pr = 0; pr < 4; ++pr) {
        float l = lgp[(row0 + pr * 32 + bl32) * Vsz + v];
        ai[pr] += l * w0; af[pr] += l * w1; ag[pr] += l * w2; ao[pr] += l * w3;
      }
    }
  }

#pragma unroll
  for (int pr = 0; pr < 4; ++pr) {
    int brow = pr * 32 + bl32;
    int bg = row0 + brow;
    const float* gr = &gt[brow * 68 + 4 * h16];
    float xi = gr[0] + bi + ai[pr], xf = gr[1] + bf_ + af[pr];
    float xg = gr[2] + bg_ + ag[pr], xo = gr[3] + bo + ao[pr];
    if (mode == 1) {
      int tok = x[(bg * SQL + tstep) * xstride];
      const float* wv = wihT2 + (long)tok * G4H + col0 + 4 * h16;
      xi += wv[0]; xf += wv[1]; xg += wv[2]; xo += wv[3];
    }
    long ci = (long)bg * Hdim + hh_g;
    float cn = sigm(xf) * c[ci] + sigm(xi) * tanhf(xg);
    float hn = sigm(xo) * tanhf(cn);
    c[ci] = cn;
    hf[ci] = hn;
    i8 q1, q2;
    quant2(hn * 127.0f, q1, q2);
    o1[ci] = q1;
    o2[ci] = q2;
  }
#undef LOADQ
#undef WRITEQ
#undef COMPUTE
}

// ---------------- logits = src @ W_proj.T (fp32, latency-optimized) --------
// One block per batch row. Each lane caches its 32 h-values (8 float4) in
// registers; per v-row: 8 unrolled coalesced float4 loads of W_proj (all in
// flight), 32 FMAs, 6-step shuffle reduce. Was 273us (serial load chain);
// now ~400cyc x 24 v/wave.
__global__ __launch_bounds__(256) void k_logits(const float* __restrict__ src,
                                                const float* __restrict__ Wp,
                                                float* __restrict__ lg,
                                                float* __restrict__ outp) {
  const int b = blockIdx.x, tid = threadIdx.x;
  const int wv = tid >> 6, ln = tid & 63;

  float4 hreg[8];
  const float4* srcv = (const float4*)(src + (long)b * Hdim);
#pragma unroll
  for (int i = 0; i < 8; ++i) hreg[i] = srcv[ln + 64 * i];

  for (int v = wv; v < Vsz; v += 4) {
    const float4* wrow = (const float4*)(Wp + (long)v * Hdim);
    float s = 0.f;
#pragma unroll
    for (int i = 0; i < 8; ++i) {
      float4 w = wrow[ln + 64 * i];
      s += w.x * hreg[i].x + w.y * hreg[i].y + w.z * hreg[i].z + w.w * hreg[i].w;
    }
#pragma unroll
    for (int off = 32; off; off >>= 1) s += __shfl_down(s, off);
    if (ln == 0) {
      lg[b * Vsz + v] = s;
      outp[b * Vsz + v] = s;
    }
  }
}

// ---------------- host ----------------
extern "C" void kernel_launch(void* const* d_in, const int* in_sizes, int n_in,
                              void* d_out, int out_size, void* d_ws, size_t ws_size,
                              hipStream_t stream) {
  const int* x = (const int*)d_in[0];
  const float* W_ih = (const float*)d_in[1];
  const float* W_hh = (const float*)d_in[2];
  const float* b_ih = (const float*)d_in[3];
  const float* b_hh = (const float*)d_in[4];
  const float* W_proj = (const float*)d_in[5];
  float* out = (float*)d_out;

  int xstride = (in_sizes[0] > Bsz * SQL) ? 2 : 1;

  // workspace layout (~45 MB)
  i8* w1 = (i8*)d_ws;
  i8* w2 = w1 + (long)G4H * Hdim;
  float* wihT2 = (float*)(w2 + (long)G4H * Hdim);
  float* bias2 = wihT2 + (long)Vsz * G4H;
  float* hf = bias2 + G4H;
  float* c = hf + (long)Bsz * Hdim;
  float* outq = c + (long)Bsz * Hdim;
  float* lg = outq + (long)Bsz * Hdim;
  i8* h1A = (i8*)(lg + Bsz * Vsz);
  i8* h2A = h1A + (long)Bsz * Hdim;
  i8* h1B = h2A + (long)Bsz * Hdim;
  i8* h2B = h1B + (long)Bsz * Hdim;

  k_split2<<<4096, 256, 0, stream>>>(W_hh, w1, w2);
  k_prep<<<3040, 256, 0, stream>>>(W_ih, b_ih, b_hh, wihT2, bias2, hf, h1A, h2A);

  // zero c (poisoned workspace)
  hipMemsetAsync(c, 0, (long)Bsz * Hdim * sizeof(float), stream);

  i8* i1[2] = {h1A, h1B};
  i8* i2[2] = {h2A, h2B};
  int pp = 0;

  // Phase 1: question (one-hot gather fused into epilogue)
  for (int t = 0; t < SQL; ++t) {
    k_step<<<256, 512, 0, stream>>>(i1[pp], i2[pp], w1, w2, bias2, wihT2,
                                    nullptr, x, t, xstride, 1, c, hf,
                                    i1[pp ^ 1], i2[pp ^ 1]);
    pp ^= 1;
  }
  hipMemcpyAsync(outq, hf, (long)Bsz * Hdim * sizeof(float),
                 hipMemcpyDeviceToDevice, stream);

  // Phase 2: thinking (zero input)
  for (int t = 0; t < TSTEPS; ++t) {
    k_step<<<256, 512, 0, stream>>>(i1[pp], i2[pp], w1, w2, bias2, wihT2,
                                    nullptr, nullptr, 0, 1, 0, c, hf,
                                    i1[pp ^ 1], i2[pp ^ 1]);
    pp ^= 1;
  }

  // Phase 3: autoregressive answer (logits fed back; ic fused in epilogue)
  for (int s = 0; s < ASTEPS; ++s) {
    const float* src = (s == 0) ? outq : hf;
    k_logits<<<Bsz, 256, 0, stream>>>(src, W_proj, lg, out + (long)s * Bsz * Vsz);
    k_step<<<256, 512, 0, stream>>>(i1[pp], i2[pp], w1, w2, bias2, wihT2,
                                    lg, nullptr, 0, 1, 2, c, hf,
                                    i1[pp ^ 1], i2[pp ^ 1]);
    pp ^= 1;
  }
}